// Round 4
// baseline (925.094 us; speedup 1.0000x reference)
//
#include <hip/hip_runtime.h>
#include <hip/hip_fp16.h>
#include <math.h>

// ---------------------------------------------------------------------------
// FusionHead: concat(emb[131072,768], tp[131072,3]) -> LayerNorm(771)
//             -> Linear(771->96) -> GELU(exact erf) -> Linear(96->3)
//
// R1: fold gamma/beta into W1; LN is linear in x -> MFMA raw f16, fix per-row
//     in epilogue: ((x-mu)*s)@W' = s*(x@W') - s*mu*colsum.
// R3: B staged through LDS chunks (30 KB) -> fusion ~144 us, still 2.2x off
//     the 64 us HBM floor. Limiter: per-chunk __syncthreads drains vmcnt(0),
//     so A-load MLP never spans a chunk boundary (~3 KB outstanding/CU).
// R4: stage FULL B (153.6 KB f16) into LDS once, then a barrier-free A
//     stream. Persistent: 256 blocks (1/CU) x 512 thr (8 waves), 4 tiles/wave,
//     3-deep chunk pipeline -> loads stay in flight across chunks AND tiles.
// ---------------------------------------------------------------------------

typedef _Float16 half8 __attribute__((ext_vector_type(8)));
typedef float floatx4 __attribute__((ext_vector_type(4)));

#define E_DIM 768
#define D_DIM 771
#define H_DIM 96
#define KSTEPS 25                        // 25 * 32 = 800 padded K
#define WB_ELEMS (KSTEPS * 6 * 64 * 8)   // fragment-packed W1': 76800 f16 = 153600 B

// Pack W1' = gamma[k] * W1[k][n] into MFMA B-fragment order, zero-pad k>=771.
// Layout: wB[t][n0][lane][j]; lane needs B[k = t*32 + (lane>>4)*8 + j][n = n0*16 + (lane&15)]
__global__ void pack_w1(const float* __restrict__ w1, const float* __restrict__ gamma,
                        _Float16* __restrict__ wB) {
    int idx = blockIdx.x * 256 + threadIdx.x;   // 300 blocks * 256 = 76800 exact
    int j = idx & 7;
    int l = (idx >> 3) & 63;
    int tn = idx >> 9;          // t*6 + n0
    int t = tn / 6;
    int n0 = tn - t * 6;
    int k = t * 32 + ((l >> 4) << 3) + j;
    int n = n0 * 16 + (l & 15);
    float v = 0.f;
    if (k < D_DIM) v = w1[k * H_DIM + n] * gamma[k];
    wB[idx] = (_Float16)v;
}

// b1p[n] = b1[n] + sum_k beta[k]*W1[k][n];  colsum[n] = sum_k gamma[k]*W1[k][n]
__global__ void make_vecs(const float* __restrict__ w1, const float* __restrict__ gamma,
                          const float* __restrict__ beta, const float* __restrict__ b1,
                          float* __restrict__ b1p, float* __restrict__ colsum) {
    int n = blockIdx.x;
    int l = threadIdx.x;
    float accb = 0.f, accg = 0.f;
    for (int k = l; k < D_DIM; k += 64) {
        float w = w1[k * H_DIM + n];
        accb += beta[k] * w;
        accg += gamma[k] * w;
    }
#pragma unroll
    for (int d = 1; d < 64; d <<= 1) {
        accb += __shfl_xor(accb, d, 64);
        accg += __shfl_xor(accg, d, 64);
    }
    if (l == 0) { b1p[n] = accb + b1[n]; colsum[n] = accg; }
}

// Load 5 K-steps (chunk c, literal) of this wave's A rows into slot s.
#define LOAD_CHUNK(s, c)                                                        \
    {                                                                           \
        _Pragma("unroll")                                                       \
        for (int tt = 0; tt < 5; ++tt) {                                        \
            const int t = (c) * 5 + tt;                                         \
            if (t < 24) {                                                       \
                xa[s][tt] = *(const floatx4*)(erow + t * 32 + q * 8);           \
                xb[s][tt] = *(const floatx4*)(erow + t * 32 + q * 8 + 4);       \
            } else {                                                            \
                float v0 = 0.f, v1 = 0.f, v2 = 0.f;                             \
                if (q == 0) { const float* tpr = tp + r * 3;                    \
                              v0 = tpr[0]; v1 = tpr[1]; v2 = tpr[2]; }          \
                xa[s][tt] = (floatx4){v0, v1, v2, 0.f};                         \
                xb[s][tt] = (floatx4){0.f, 0.f, 0.f, 0.f};                      \
            }                                                                   \
        }                                                                       \
    }

// Stats + f16 convert + 30 MFMAs for chunk c (literal) from slot s.
#define COMPUTE_CHUNK(s, c)                                                     \
    {                                                                           \
        _Pragma("unroll")                                                       \
        for (int tt = 0; tt < 5; ++tt) {                                        \
            const int t = (c) * 5 + tt;                                         \
            floatx4 x0 = xa[s][tt], x1 = xb[s][tt];                             \
            sum += (x0.x + x0.y) + (x0.z + x0.w);                               \
            sum += (x1.x + x1.y) + (x1.z + x1.w);                               \
            ss += x0.x * x0.x; ss += x0.y * x0.y; ss += x0.z * x0.z; ss += x0.w * x0.w; \
            ss += x1.x * x1.x; ss += x1.y * x1.y; ss += x1.z * x1.z; ss += x1.w * x1.w; \
            half8 a;                                                            \
            a[0] = (_Float16)x0.x; a[1] = (_Float16)x0.y;                       \
            a[2] = (_Float16)x0.z; a[3] = (_Float16)x0.w;                       \
            a[4] = (_Float16)x1.x; a[5] = (_Float16)x1.y;                       \
            a[6] = (_Float16)x1.z; a[7] = (_Float16)x1.w;                       \
            _Pragma("unroll")                                                   \
            for (int n0 = 0; n0 < 6; ++n0) {                                    \
                half8 b = *(const half8*)&bufB[((t * 6 + n0) * 64 + lane) * 8]; \
                acc[n0] = __builtin_amdgcn_mfma_f32_16x16x32_f16(a, b, acc[n0], 0, 0, 0); \
            }                                                                   \
        }                                                                       \
    }

__global__ __launch_bounds__(512, 2) void fusion_main(
    const float* __restrict__ emb, const float* __restrict__ tp,
    const _Float16* __restrict__ wB, const float* __restrict__ b1p,
    const float* __restrict__ colsum,
    const float* __restrict__ w2, const float* __restrict__ b2,
    float* __restrict__ out)
{
    extern __shared__ _Float16 bufB[];       // 153600 B: full fragment-packed W1'

    const int tid = threadIdx.x;

    // ---- stage ALL of B into LDS, once ----
    {
        const float4* __restrict__ src = (const float4*)wB;
        float4* dst = (float4*)bufB;
        for (int g = tid; g < WB_ELEMS / 8; g += 512) dst[g] = src[g];
    }
    __syncthreads();                          // the ONLY barrier

    const int lane = tid & 63;
    const int wv = tid >> 6;
    const int m = lane & 15;        // A: row in 16-row tile; C: col n within tile
    const int q = lane >> 4;        // A/B: k-group; C: row group

    // ---- epilogue constants (same for all tiles) ----
    float b1v[6], csv[6], w2v[6][3];
#pragma unroll
    for (int n0 = 0; n0 < 6; ++n0) {
        int n = n0 * 16 + m;
        b1v[n0] = b1p[n];
        csv[n0] = colsum[n];
        w2v[n0][0] = w2[n * 3 + 0];
        w2v[n0][1] = w2[n * 3 + 1];
        w2v[n0][2] = w2[n * 3 + 2];
    }
    const float b20 = b2[0], b21 = b2[1], b22 = b2[2];
    const float kInvSqrt2 = 0.70710678118654752f;
    const float inv_n = 1.0f / 771.0f;

    const long blockRow = (long)blockIdx.x * 512;

#pragma unroll 1
    for (int tile = 0; tile < 4; ++tile) {
        const long rowBase = blockRow + (long)(tile * 8 + wv) * 16;
        const long r = rowBase + m;
        const float* erow = emb + r * (long)E_DIM;

        floatx4 acc[6];
#pragma unroll
        for (int n0 = 0; n0 < 6; ++n0) acc[n0] = (floatx4){0.f, 0.f, 0.f, 0.f};
        float sum = 0.f, ss = 0.f;

        floatx4 xa[3][5], xb[3][5];           // 3-deep chunk pipeline
        LOAD_CHUNK(0, 0)
        LOAD_CHUNK(1, 1)
        LOAD_CHUNK(2, 2)
        COMPUTE_CHUNK(0, 0)
        LOAD_CHUNK(0, 3)
        COMPUTE_CHUNK(1, 1)
        LOAD_CHUNK(1, 4)
        COMPUTE_CHUNK(2, 2)
        COMPUTE_CHUNK(0, 3)
        COMPUTE_CHUNK(1, 4)

        // ---- row stats: reduce over the 4 quads holding the same row ----
        sum += __shfl_xor(sum, 16, 64);  ss += __shfl_xor(ss, 16, 64);
        sum += __shfl_xor(sum, 32, 64);  ss += __shfl_xor(ss, 32, 64);
        float mean = sum * inv_n;
        float var = ss * inv_n - mean * mean;
        float sc = rsqrtf(var + 1e-5f);

        // ---- epilogue: LN affine fix + b1', exact GELU, 96->3, reduce ----
        // C layout: col n = n0*16 + m, row = q*4 + reg.
#pragma unroll
        for (int reg = 0; reg < 4; ++reg) {
            int row = q * 4 + reg;
            float mu_r = __shfl(mean, row, 64);   // lane 'row' has m==row
            float sc_r = __shfl(sc, row, 64);
            float r0 = 0.f, r1 = 0.f, r2 = 0.f;
#pragma unroll
            for (int n0 = 0; n0 < 6; ++n0) {
                float h = sc_r * (acc[n0][reg] - mu_r * csv[n0]) + b1v[n0];
                h = 0.5f * h * (1.0f + erff(h * kInvSqrt2));
                r0 += h * w2v[n0][0];
                r1 += h * w2v[n0][1];
                r2 += h * w2v[n0][2];
            }
#pragma unroll
            for (int d = 1; d < 16; d <<= 1) {
                r0 += __shfl_xor(r0, d, 64);
                r1 += __shfl_xor(r1, d, 64);
                r2 += __shfl_xor(r2, d, 64);
            }
            if (m == 0) {
                long orow = rowBase + row;
                out[orow * 3 + 0] = r0 + b20;
                out[orow * 3 + 1] = r1 + b21;
                out[orow * 3 + 2] = r2 + b22;
            }
        }
    }
}

extern "C" void kernel_launch(void* const* d_in, const int* in_sizes, int n_in,
                              void* d_out, int out_size, void* d_ws, size_t ws_size,
                              hipStream_t stream) {
    const float* emb   = (const float*)d_in[0];   // [131072,768]
    const float* tp    = (const float*)d_in[1];   // [131072,3]
    const float* gamma = (const float*)d_in[2];   // [771]
    const float* beta  = (const float*)d_in[3];   // [771]
    const float* w1    = (const float*)d_in[4];   // [771,96]
    const float* b1    = (const float*)d_in[5];   // [96]
    const float* w2    = (const float*)d_in[6];   // [96,3]
    const float* b2    = (const float*)d_in[7];   // [3]
    float* out = (float*)d_out;

    _Float16* wB = (_Float16*)d_ws;                                        // 153600 B
    float* b1p    = (float*)((char*)d_ws + WB_ELEMS * sizeof(_Float16));   // 384 B
    float* colsum = b1p + H_DIM;                                           // 384 B

    // allow >64 KB dynamic LDS (153600 B) — idempotent, capture-safe
    hipFuncSetAttribute((const void*)fusion_main,
                        hipFuncAttributeMaxDynamicSharedMemorySize, 160 * 1024);

    hipLaunchKernelGGL(pack_w1, dim3(WB_ELEMS / 256), dim3(256), 0, stream, w1, gamma, wB);
    hipLaunchKernelGGL(make_vecs, dim3(H_DIM), dim3(64), 0, stream, w1, gamma, beta, b1, b1p, colsum);
    hipLaunchKernelGGL(fusion_main, dim3(256), dim3(512), WB_ELEMS * sizeof(_Float16), stream,
                       emb, tp, wB, b1p, colsum, w2, b2, out);
}